// Round 1
// baseline (92.946 us; speedup 1.0000x reference)
//
#include <hip/hip_runtime.h>

#define NB 64
#define KP1 129
#define DD 128
#define NROWS 50000
#define EPSF 1e-6f
#define OUT_SIDE (NB*NB*KP1)            // 528384 per side
#define L2E_T 28.853900817779268f       // log2(e)/T, T=0.05
#define RSQRT_D 0.08838834764831845f    // 1/sqrt(128)

__device__ __forceinline__ float4 ldf4(const float* p) { return *(const float4*)p; }

// Fused: 512 compute blocks (2 sides x 64 a x 4 b-tiles) + 512 bank-copy blocks.
__global__ __launch_bounds__(256) void k_main(
    const float* __restrict__ v1, const float* __restrict__ v2,
    const float* __restrict__ mem1, const float* __restrict__ mem2,
    const int* __restrict__ y, const int* __restrict__ idx,
    float* __restrict__ dout, double* __restrict__ sums)
{
    const int bid = blockIdx.x;
    const int tid = threadIdx.x;

    if (bid < 512) {
        // ---------------- compute role ----------------
        __shared__ int    lidx[KP1];
        __shared__ double lsum[4];

        const int s    = bid >> 8;        // side: 0 -> (v1, mem2), 1 -> (v2, mem1)
        const int a    = (bid & 255) >> 2;
        const int tile = bid & 3;
        const float* v   = s ? v2 : v1;
        const float* mem = s ? mem1 : mem2;
        float* outp = dout + (size_t)s * OUT_SIDE;

        const int* idxa = idx + a * KP1;
        if (tid < KP1) lidx[tid] = idxa[tid];

        const int lane = tid & 63;
        const int wave = tid >> 6;
        const int g    = lane >> 4;       // 4 b's per wave
        const int j    = lane & 15;       // 16 lanes per b, 8 elems each
        const int b    = tile * 16 + wave * 4 + g;
        const int dbase = j * 8;

        const int yb = y[b];

        // phase A: arn = normalize(v[a]-anchor[b]+eps), keep (anchor-eps), arn in regs
        float vv[8], an[8];
        {
            const float* vp = v + a * DD + dbase;
            const float* ap = mem + (size_t)yb * DD + dbase;
            float4 t0 = ldf4(vp), t1 = ldf4(vp + 4);
            float4 u0 = ldf4(ap), u1 = ldf4(ap + 4);
            vv[0]=t0.x; vv[1]=t0.y; vv[2]=t0.z; vv[3]=t0.w;
            vv[4]=t1.x; vv[5]=t1.y; vv[6]=t1.z; vv[7]=t1.w;
            an[0]=u0.x; an[1]=u0.y; an[2]=u0.z; an[3]=u0.w;
            an[4]=u1.x; an[5]=u1.y; an[6]=u1.z; an[7]=u1.w;
        }
        float df[8];
        float ss = 0.f, sd = 0.f;
        #pragma unroll
        for (int i = 0; i < 8; ++i) {
            df[i] = vv[i] - an[i] + EPSF;
            ss = fmaf(df[i], df[i], ss);
            sd += df[i];
        }
        #pragma unroll
        for (int m = 1; m < 16; m <<= 1) {
            ss += __shfl_xor(ss, m, 64);
            sd += __shfl_xor(sd, m, 64);
        }
        const float rn = 1.0f / fmaxf(sqrtf(ss), 1e-12f);
        float arn[8], am[8];
        #pragma unroll
        for (int i = 0; i < 8; ++i) { arn[i] = df[i] * rn; am[i] = an[i] - EPSF; }
        // exact value when weight row == anchor row: exp((sum(arn)/sqrt(D))/T)
        const float vem = exp2f(sd * rn * (RSQRT_D * L2E_T));

        __syncthreads();

        double acc = 0.0;
        int wi = lidx[0];
        {
            const float* wp = mem + (size_t)wi * DD + dbase;
            float4 w0 = ldf4(wp), w1 = ldf4(wp + 4);
            for (int k = 0; k < KP1; ++k) {
                int win = 0; float4 n0 = {0,0,0,0}, n1 = {0,0,0,0};
                if (k + 1 < KP1) {
                    win = lidx[k + 1];
                    const float* npp = mem + (size_t)win * DD + dbase;
                    n0 = ldf4(npp); n1 = ldf4(npp + 4);
                }
                float w[8] = {w0.x,w0.y,w0.z,w0.w,w1.x,w1.y,w1.z,w1.w};
                float s2 = 0.f, dt = 0.f;
                #pragma unroll
                for (int i = 0; i < 8; ++i) {
                    float d = w[i] - am[i];           // = w - anchor + eps
                    s2 = fmaf(d, d, s2);
                    dt = fmaf(d, arn[i], dt);
                }
                #pragma unroll
                for (int m = 1; m < 16; m <<= 1) {
                    s2 += __shfl_xor(s2, m, 64);
                    dt += __shfl_xor(dt, m, 64);
                }
                const float rw  = 1.0f / fmaxf(sqrtf(s2), 1e-12f);
                const float val = (wi == yb) ? vem : exp2f(dt * rw * L2E_T);
                if (j == 0) {
                    outp[(size_t)(a * NB + b) * KP1 + k] = val;
                    acc += (double)val;
                }
                wi = win; w0 = n0; w1 = n1;
            }
        }
        // lanes 0,16,32,48 hold partials
        acc += __shfl_xor(acc, 16, 64);
        acc += __shfl_xor(acc, 32, 64);
        if (lane == 0) lsum[wave] = acc;
        __syncthreads();
        if (tid == 0) atomicAdd(&sums[s], lsum[0] + lsum[1] + lsum[2] + lsum[3]);
    } else {
        // ---------------- bank copy role (overlaps HBM with compute VALU) ----------------
        float* nm1 = dout + (size_t)2 * OUT_SIDE;
        float* nm2 = nm1 + (size_t)NROWS * DD;
        const int cid = bid - 512;                    // 0..511
        const size_t nf4 = (size_t)NROWS * DD / 4;    // 1,600,000 per bank
        const float4* s1 = (const float4*)mem1;
        const float4* s2 = (const float4*)mem2;
        float4* d1 = (float4*)nm1;
        float4* d2 = (float4*)nm2;
        for (size_t i = (size_t)cid * 256 + tid; i < nf4; i += (size_t)512 * 256) {
            d1[i] = s1[i];
            d2[i] = s2[i];
        }
    }
}

// Finish: scale out by 1/Z per side; patch the 128 momentum-updated rows.
__global__ __launch_bounds__(256) void k_finish(
    const float* __restrict__ v1, const float* __restrict__ v2,
    const float* __restrict__ mem1, const float* __restrict__ mem2,
    const int* __restrict__ y,
    float* __restrict__ dout, const double* __restrict__ sums)
{
    const int bid = blockIdx.x;
    const int tid = threadIdx.x;

    if (bid < 32) {
        // patch blocks: 2 banks x 64 b, one b per wave
        const int bank = bid >> 4;
        const int wave = tid >> 6;
        const int lane = tid & 63;
        const int b    = (bid & 15) * 4 + wave;
        const float* mem = bank ? mem2 : mem1;
        const float* v   = bank ? v2 : v1;
        float* nm = dout + (size_t)2 * OUT_SIDE + (size_t)bank * NROWS * DD;

        const int row = y[b];
        bool skip = false;
        for (int b2 = b + 1; b2 < NB; ++b2) skip |= (y[b2] == row);  // last occurrence wins
        if (!skip) {
            const float2 m2 = *(const float2*)(mem + (size_t)row * DD + lane * 2);
            const float2 w2 = *(const float2*)(v + (size_t)b * DD + lane * 2);
            float px = 0.5f * (m2.x + w2.x);
            float py = 0.5f * (m2.y + w2.y);
            float ss = px * px + py * py;
            #pragma unroll
            for (int m = 1; m < 64; m <<= 1) ss += __shfl_xor(ss, m, 64);
            const float rn = 1.0f / sqrtf(ss);
            *(float2*)(nm + (size_t)row * DD + lane * 2) = make_float2(px * rn, py * rn);
        }
    } else {
        // scale blocks: 1032 blocks x 256 threads x 1 float4 = 264192 float4 exactly
        const size_t i = (size_t)(bid - 32) * 256 + tid;   // float4 index
        const int side = (i >= (size_t)OUT_SIDE / 4) ? 1 : 0;
        const double sm = sums[side];
        const float f = (float)((double)OUT_SIDE / (sm * (double)NROWS));
        float4* io = (float4*)dout;
        float4 t = io[i];
        t.x *= f; t.y *= f; t.z *= f; t.w *= f;
        io[i] = t;
    }
}

extern "C" void kernel_launch(void* const* d_in, const int* in_sizes, int n_in,
                              void* d_out, int out_size, void* d_ws, size_t ws_size,
                              hipStream_t stream) {
    const float* v1   = (const float*)d_in[0];
    const float* v2   = (const float*)d_in[1];
    const float* mem1 = (const float*)d_in[2];
    const float* mem2 = (const float*)d_in[3];
    const int*   y    = (const int*)d_in[4];
    const int*   idx  = (const int*)d_in[5];
    float*  out  = (float*)d_out;
    double* sums = (double*)d_ws;

    hipMemsetAsync(d_ws, 0, 2 * sizeof(double), stream);
    k_main<<<1024, 256, 0, stream>>>(v1, v2, mem1, mem2, y, idx, out, sums);
    k_finish<<<32 + (2 * OUT_SIDE / 4) / 256, 256, 0, stream>>>(v1, v2, mem1, mem2, y, out, sums);
}

// Round 3
// 65.860 us; speedup vs baseline: 1.4113x; 1.4113x over previous
//
#include <hip/hip_runtime.h>

#define NB 64
#define KP1 129
#define DD 128
#define NROWS 50000
#define EPSF 1e-6f
#define OUT_SIDE (NB*NB*KP1)            // 528384 per side
#define L2E_T 28.853900817779268f       // log2(e)/T, T=0.05
#define RSQRT_D 0.08838834764831845f    // 1/sqrt(128)

#define NCHUNK 4
#define NCOMPUTE (2*64*4*NCHUNK)        // 2048 compute blocks
#define NCOPY 512
#define NSLOT 32                        // atomic slots per side

__device__ __forceinline__ float4 ldf4(const float* p) { return *(const float4*)p; }

// Fused: 2048 compute blocks (2 sides x 64 a x 4 b-tiles x 4 k-chunks) + 512 copy blocks.
__global__ __launch_bounds__(256) void k_main(
    const float* __restrict__ v1, const float* __restrict__ v2,
    const float* __restrict__ mem1, const float* __restrict__ mem2,
    const int* __restrict__ y, const int* __restrict__ idx,
    float* __restrict__ dout, double* __restrict__ sums)
{
    const int bid = blockIdx.x;
    const int tid = threadIdx.x;

    if (bid < NCOMPUTE) {
        // ---------------- compute role ----------------
        __shared__ int    lidx[KP1];
        __shared__ double lsum[4];

        const int s     = bid >> 10;      // side: 0 -> (v1, mem2), 1 -> (v2, mem1)
        const int a     = (bid >> 4) & 63;
        const int tile  = (bid >> 2) & 3;
        const int chunk = bid & 3;
        const int k0 = (chunk * KP1) / NCHUNK;
        const int k1 = ((chunk + 1) * KP1) / NCHUNK;

        const float* v   = s ? v2 : v1;
        const float* mem = s ? mem1 : mem2;
        float* outp = dout + (size_t)s * OUT_SIDE;

        const int* idxa = idx + a * KP1;
        if (tid < KP1) lidx[tid] = idxa[tid];

        const int lane = tid & 63;
        const int wave = tid >> 6;
        const int g    = lane >> 4;       // 4 b's per wave
        const int j    = lane & 15;       // 16 lanes per b, 8 elems each
        const int b    = tile * 16 + wave * 4 + g;
        const int dbase = j * 8;

        const int yb = y[b];

        // phase A: arn = normalize(v[a]-anchor[b]+eps); keep (anchor-eps), arn in regs
        float vv[8], an[8];
        {
            const float* vp = v + a * DD + dbase;
            const float* ap = mem + (size_t)yb * DD + dbase;
            float4 t0 = ldf4(vp), t1 = ldf4(vp + 4);
            float4 u0 = ldf4(ap), u1 = ldf4(ap + 4);
            vv[0]=t0.x; vv[1]=t0.y; vv[2]=t0.z; vv[3]=t0.w;
            vv[4]=t1.x; vv[5]=t1.y; vv[6]=t1.z; vv[7]=t1.w;
            an[0]=u0.x; an[1]=u0.y; an[2]=u0.z; an[3]=u0.w;
            an[4]=u1.x; an[5]=u1.y; an[6]=u1.z; an[7]=u1.w;
        }
        float df[8];
        float ss = 0.f, sd = 0.f;
        #pragma unroll
        for (int i = 0; i < 8; ++i) {
            df[i] = vv[i] - an[i] + EPSF;
            ss = fmaf(df[i], df[i], ss);
            sd += df[i];
        }
        #pragma unroll
        for (int m = 1; m < 16; m <<= 1) {
            ss += __shfl_xor(ss, m, 64);
            sd += __shfl_xor(sd, m, 64);
        }
        const float rn = 1.0f / fmaxf(sqrtf(ss), 1e-12f);
        float arn[8], am[8];
        #pragma unroll
        for (int i = 0; i < 8; ++i) { arn[i] = df[i] * rn; am[i] = an[i] - EPSF; }
        // exact value when weight row == anchor row: exp((sum(arn)/sqrt(D))/T)
        const float vem = exp2f(sd * rn * (RSQRT_D * L2E_T));

        __syncthreads();

        double acc = 0.0;                 // after loop: every lane of a group holds S_g
        int wi = lidx[k0];
        {
            const float* wp = mem + (size_t)wi * DD + dbase;
            float4 w0 = ldf4(wp), w1 = ldf4(wp + 4);
            for (int k = k0; k < k1; ++k) {
                int win = 0; float4 n0 = {0,0,0,0}, n1 = {0,0,0,0};
                if (k + 1 < k1) {
                    win = lidx[k + 1];
                    const float* npp = mem + (size_t)win * DD + dbase;
                    n0 = ldf4(npp); n1 = ldf4(npp + 4);
                }
                float w[8] = {w0.x,w0.y,w0.z,w0.w,w1.x,w1.y,w1.z,w1.w};
                float s2 = 0.f, dt = 0.f;
                #pragma unroll
                for (int i = 0; i < 8; ++i) {
                    float d = w[i] - am[i];           // = w - anchor + eps
                    s2 = fmaf(d, d, s2);
                    dt = fmaf(d, arn[i], dt);
                }
                #pragma unroll
                for (int m = 1; m < 16; m <<= 1) {
                    s2 += __shfl_xor(s2, m, 64);
                    dt += __shfl_xor(dt, m, 64);
                }
                const float rw  = 1.0f / fmaxf(sqrtf(s2), 1e-12f);
                const float val = (wi == yb) ? vem : exp2f(dt * rw * L2E_T);
                if (j == 0) outp[(size_t)(a * NB + b) * KP1 + k] = val;
                acc += (double)val;       // val is lane-uniform within the 16-lane group
                wi = win; w0 = n0; w1 = n1;
            }
        }
        // Cross-group reduce: lane^16 and lane^32 sum ONE lane position per group,
        // so the result is S_0+S_1+S_2+S_3 — no division by 16 (each lane already
        // holds its full group sum, and within-group lanes are never summed).
        acc += __shfl_xor(acc, 16, 64);
        acc += __shfl_xor(acc, 32, 64);
        if (lane == 0) lsum[wave] = acc;
        __syncthreads();
        if (tid == 0)
            atomicAdd(&sums[s * NSLOT + (bid & (NSLOT - 1))],
                      lsum[0] + lsum[1] + lsum[2] + lsum[3]);
    } else {
        // ---------------- bank copy role (overlaps HBM with compute VALU) ----------------
        float* nm1 = dout + (size_t)2 * OUT_SIDE;
        float* nm2 = nm1 + (size_t)NROWS * DD;
        const int cid = bid - NCOMPUTE;               // 0..511
        const size_t nf4 = (size_t)NROWS * DD / 4;    // 1,600,000 per bank
        const float4* s1 = (const float4*)mem1;
        const float4* s2 = (const float4*)mem2;
        float4* d1 = (float4*)nm1;
        float4* d2 = (float4*)nm2;
        for (size_t i = (size_t)cid * 256 + tid; i < nf4; i += (size_t)NCOPY * 256) {
            d1[i] = s1[i];
            d2[i] = s2[i];
        }
    }
}

// Finish: scale out by 1/Z per side; patch the 128 momentum-updated rows.
__global__ __launch_bounds__(256) void k_finish(
    const float* __restrict__ v1, const float* __restrict__ v2,
    const float* __restrict__ mem1, const float* __restrict__ mem2,
    const int* __restrict__ y,
    float* __restrict__ dout, const double* __restrict__ sums)
{
    const int bid = blockIdx.x;
    const int tid = threadIdx.x;

    if (bid < 32) {
        // patch blocks: 2 banks x 64 b, one b per wave
        const int bank = bid >> 4;
        const int wave = tid >> 6;
        const int lane = tid & 63;
        const int b    = (bid & 15) * 4 + wave;
        const float* mem = bank ? mem2 : mem1;
        const float* v   = bank ? v2 : v1;
        float* nm = dout + (size_t)2 * OUT_SIDE + (size_t)bank * NROWS * DD;

        const int row = y[b];
        bool skip = false;
        for (int b2 = b + 1; b2 < NB; ++b2) skip |= (y[b2] == row);  // last occurrence wins
        if (!skip) {
            const float2 m2 = *(const float2*)(mem + (size_t)row * DD + lane * 2);
            const float2 w2 = *(const float2*)(v + (size_t)b * DD + lane * 2);
            float px = 0.5f * (m2.x + w2.x);
            float py = 0.5f * (m2.y + w2.y);
            float ss = px * px + py * py;
            #pragma unroll
            for (int m = 1; m < 64; m <<= 1) ss += __shfl_xor(ss, m, 64);
            const float rn = 1.0f / sqrtf(ss);
            *(float2*)(nm + (size_t)row * DD + lane * 2) = make_float2(px * rn, py * rn);
        }
    } else {
        // scale blocks: 1032 blocks x 256 threads x 1 float4 = 264192 float4 exactly
        const size_t i = (size_t)(bid - 32) * 256 + tid;   // float4 index
        const int side = (i >= (size_t)OUT_SIDE / 4) ? 1 : 0;
        double sm = 0.0;
        #pragma unroll
        for (int q = 0; q < NSLOT; ++q) sm += sums[side * NSLOT + q];
        const float f = (float)((double)OUT_SIDE / (sm * (double)NROWS));
        float4* io = (float4*)dout;
        float4 t = io[i];
        t.x *= f; t.y *= f; t.z *= f; t.w *= f;
        io[i] = t;
    }
}

extern "C" void kernel_launch(void* const* d_in, const int* in_sizes, int n_in,
                              void* d_out, int out_size, void* d_ws, size_t ws_size,
                              hipStream_t stream) {
    const float* v1   = (const float*)d_in[0];
    const float* v2   = (const float*)d_in[1];
    const float* mem1 = (const float*)d_in[2];
    const float* mem2 = (const float*)d_in[3];
    const int*   y    = (const int*)d_in[4];
    const int*   idx  = (const int*)d_in[5];
    float*  out  = (float*)d_out;
    double* sums = (double*)d_ws;

    hipMemsetAsync(d_ws, 0, 2 * NSLOT * sizeof(double), stream);
    k_main<<<NCOMPUTE + NCOPY, 256, 0, stream>>>(v1, v2, mem1, mem2, y, idx, out, sums);
    k_finish<<<32 + (2 * OUT_SIDE / 4) / 256, 256, 0, stream>>>(v1, v2, mem1, mem2, y, out, sums);
}

// Round 4
// 38.308 us; speedup vs baseline: 2.4263x; 1.7192x over previous
//
#include <hip/hip_runtime.h>

#define NB 64
#define KP1 129
#define DD 128
#define NROWS 50000
#define EPSF 1e-6f
#define E128F (128.0f*EPSF*EPSF)
#define OUT_SIDE (NB*NB*KP1)            // 528384 per side
#define L2E_T 28.853900817779268f       // log2(e)/T, T=0.05
#define RSQRT_D 0.08838834764831845f    // 1/sqrt(128)
#define NSLOT 32
#define NGEMM (2*129)                   // 2 sides x 129 rowblocks of 64 w-rows
#define NCOPY 512

__device__ __forceinline__ float4 ldf4(const float* p) { return *(const float4*)p; }

// One fused kernel: 258 gram+epilogue blocks + 512 bank-copy blocks.
// Expansion: out_raw[a,b,k] = exp(( (w·u) - (w·an) - (u·an) + ||an||^2
//            + eps*(Sw+Su-2San) + 128eps^2 ) / (||w-an+eps|| * ||u-an+eps||) / T)
__global__ __launch_bounds__(256) void k_big(
    const float* __restrict__ v1, const float* __restrict__ v2,
    const float* __restrict__ mem1, const float* __restrict__ mem2,
    const int* __restrict__ y, const int* __restrict__ idx,
    float* __restrict__ dout, double* __restrict__ sums)
{
    const int bid = blockIdx.x;
    const int tid = threadIdx.x;

    if (bid < NGEMM) {
        __shared__ float Alds[128*64];        // [d][r] w-rows, transposed
        __shared__ float Blds[128*64];        // [d][c] anchor rows, transposed
        __shared__ float4 ared[64][4];        // (w·u, Sw, Sww, -) partials per (row, chunk)
        __shared__ float4 bred[64][4];        // (San, Sanan, an·u0, an·u1) per (col, chunk)
        __shared__ float2 sured[2][4];        // (Su, Suu) partials
        __shared__ float dotwul[64], swl[64], wql[64];
        __shared__ float sanl[64], anql[64], g1l0[64], g1l1[64];
        __shared__ int   lidxl[64], yl[64];
        __shared__ float sul[2], usql[2];
        __shared__ double zred[256];

        const int s  = bid / 129;             // side: 0 -> (v1, mem2), 1 -> (v2, mem1)
        const int rb = bid % 129;
        const float* v   = s ? v2 : v1;
        const float* mem = s ? mem1 : mem2;
        const int a0 = (rb*64) / 129;
        const int a1 = (rb*64 + 63) / 129;    // a0 or a0+1

        const int r  = tid & 63;
        const int ch = tid >> 6;              // 4 d-chunks of 32

        // ---- stage A: 64 w-rows (g = rb*64 + r), compute w·u[a(g)], Sw, Sww ----
        {
            const int g    = rb*64 + r;
            const int ag   = g / 129;
            const int mrow = idx[g];
            if (ch == 0) { lidxl[r] = mrow; yl[r] = y[r]; }
            const float* ap = mem + (size_t)mrow*DD + ch*32;
            const float* up = v + (size_t)ag*DD + ch*32;
            float pd = 0.f, ps = 0.f, pq = 0.f;
            #pragma unroll
            for (int i = 0; i < 8; ++i) {
                float4 w  = ldf4(ap + i*4);
                float4 uu = ldf4(up + i*4);
                const int d = ch*32 + i*4;
                Alds[(d+0)*64 + r] = w.x;
                Alds[(d+1)*64 + r] = w.y;
                Alds[(d+2)*64 + r] = w.z;
                Alds[(d+3)*64 + r] = w.w;
                pd = fmaf(w.x,uu.x, fmaf(w.y,uu.y, fmaf(w.z,uu.z, fmaf(w.w,uu.w, pd))));
                ps += (w.x + w.y) + (w.z + w.w);
                pq = fmaf(w.x,w.x, fmaf(w.y,w.y, fmaf(w.z,w.z, fmaf(w.w,w.w, pq))));
            }
            ared[r][ch] = make_float4(pd, ps, pq, 0.f);
        }
        // ---- stage B: 64 anchor cols, compute San, ||an||^2, an·u[a0], an·u[a1] ----
        {
            const int c = r;
            const int arow = y[c];
            const float* bp  = mem + (size_t)arow*DD + ch*32;
            const float* u0p = v + (size_t)a0*DD + ch*32;
            const float* u1p = v + (size_t)a1*DD + ch*32;
            float pn = 0.f, pq = 0.f, p0 = 0.f, p1 = 0.f;
            #pragma unroll
            for (int i = 0; i < 8; ++i) {
                float4 an4 = ldf4(bp  + i*4);
                float4 u0  = ldf4(u0p + i*4);
                float4 u1  = ldf4(u1p + i*4);
                const int d = ch*32 + i*4;
                Blds[(d+0)*64 + c] = an4.x;
                Blds[(d+1)*64 + c] = an4.y;
                Blds[(d+2)*64 + c] = an4.z;
                Blds[(d+3)*64 + c] = an4.w;
                pn += (an4.x + an4.y) + (an4.z + an4.w);
                pq = fmaf(an4.x,an4.x, fmaf(an4.y,an4.y, fmaf(an4.z,an4.z, fmaf(an4.w,an4.w, pq))));
                p0 = fmaf(an4.x,u0.x, fmaf(an4.y,u0.y, fmaf(an4.z,u0.z, fmaf(an4.w,u0.w, p0))));
                p1 = fmaf(an4.x,u1.x, fmaf(an4.y,u1.y, fmaf(an4.z,u1.z, fmaf(an4.w,u1.w, p1))));
            }
            bred[c][ch] = make_float4(pn, pq, p0, p1);
        }
        // ---- stage u stats: Su, ||u||^2 for a0, a1 ----
        if (tid < 8) {
            const int au = tid & 1, c2 = tid >> 1;
            const float* up = v + (size_t)(au ? a1 : a0)*DD + c2*32;
            float ps = 0.f, pq = 0.f;
            #pragma unroll
            for (int i = 0; i < 8; ++i) {
                float4 uu = ldf4(up + i*4);
                ps += (uu.x + uu.y) + (uu.z + uu.w);
                pq = fmaf(uu.x,uu.x, fmaf(uu.y,uu.y, fmaf(uu.z,uu.z, fmaf(uu.w,uu.w, pq))));
            }
            sured[au][c2] = make_float2(ps, pq);
        }
        __syncthreads();
        if (tid < 64) {
            float4 q0 = ared[tid][0], q1 = ared[tid][1], q2 = ared[tid][2], q3 = ared[tid][3];
            dotwul[tid] = (q0.x+q1.x)+(q2.x+q3.x);
            swl[tid]    = (q0.y+q1.y)+(q2.y+q3.y);
            wql[tid]    = (q0.z+q1.z)+(q2.z+q3.z);
        } else if (tid < 128) {
            const int c = tid - 64;
            float4 q0 = bred[c][0], q1 = bred[c][1], q2 = bred[c][2], q3 = bred[c][3];
            sanl[c] = (q0.x+q1.x)+(q2.x+q3.x);
            anql[c] = (q0.y+q1.y)+(q2.y+q3.y);
            g1l0[c] = (q0.z+q1.z)+(q2.z+q3.z);
            g1l1[c] = (q0.w+q1.w)+(q2.w+q3.w);
        } else if (tid < 130) {
            const int au = tid - 128;
            float2 e0 = sured[au][0], e1 = sured[au][1], e2 = sured[au][2], e3 = sured[au][3];
            sul[au]  = (e0.x+e1.x)+(e2.x+e3.x);
            usql[au] = (e0.y+e1.y)+(e2.y+e3.y);
        }
        __syncthreads();

        // ---- GEMM: C-tile 64x64, thread tile 4r x 4c ----
        const int r0 = (tid >> 4) << 2;
        const int c0 = (tid & 15) << 2;
        float acc[4][4] = {{0.f,0.f,0.f,0.f},{0.f,0.f,0.f,0.f},{0.f,0.f,0.f,0.f},{0.f,0.f,0.f,0.f}};
        #pragma unroll 8
        for (int k = 0; k < 128; ++k) {
            float4 av = *(float4*)&Alds[k*64 + r0];
            float4 bv = *(float4*)&Blds[k*64 + c0];
            acc[0][0]=fmaf(av.x,bv.x,acc[0][0]); acc[0][1]=fmaf(av.x,bv.y,acc[0][1]);
            acc[0][2]=fmaf(av.x,bv.z,acc[0][2]); acc[0][3]=fmaf(av.x,bv.w,acc[0][3]);
            acc[1][0]=fmaf(av.y,bv.x,acc[1][0]); acc[1][1]=fmaf(av.y,bv.y,acc[1][1]);
            acc[1][2]=fmaf(av.y,bv.z,acc[1][2]); acc[1][3]=fmaf(av.y,bv.w,acc[1][3]);
            acc[2][0]=fmaf(av.z,bv.x,acc[2][0]); acc[2][1]=fmaf(av.z,bv.y,acc[2][1]);
            acc[2][2]=fmaf(av.z,bv.z,acc[2][2]); acc[2][3]=fmaf(av.z,bv.w,acc[2][3]);
            acc[3][0]=fmaf(av.w,bv.x,acc[3][0]); acc[3][1]=fmaf(av.w,bv.y,acc[3][1]);
            acc[3][2]=fmaf(av.w,bv.z,acc[3][2]); acc[3][3]=fmaf(av.w,bv.w,acc[3][3]);
        }

        // ---- epilogue: assemble, exp, write out, Z-partials ----
        float dwr[4], swr[4], wqr[4];
        int   idr[4], aur[4];
        size_t obase[4];
        #pragma unroll
        for (int i = 0; i < 4; ++i) {
            const int rr = r0 + i, gg = rb*64 + rr;
            const int aa = gg / 129, kk = gg - aa*129;
            dwr[i] = dotwul[rr]; swr[i] = swl[rr]; wqr[i] = wql[rr];
            idr[i] = lidxl[rr];  aur[i] = aa - a0;
            obase[i] = (size_t)s*OUT_SIDE + (size_t)(aa*64)*129 + kk;
        }
        double zacc = 0.0;
        #pragma unroll
        for (int j = 0; j < 4; ++j) {
            const int b = c0 + j;
            const float sanb = sanl[b], anqb = anql[b];
            const int yb = yl[b];
            const float g1v[2] = { g1l0[b], g1l1[b] };
            float rdu[2], vem[2];
            #pragma unroll
            for (int au = 0; au < 2; ++au) {
                const float du2 = usql[au] - 2.f*g1v[au] + anqb
                                + 2.f*EPSF*(sul[au] - sanb) + E128F;
                rdu[au] = rsqrtf(fmaxf(du2, 1e-20f));
                vem[au] = exp2f((sul[au] - sanb + 128.f*EPSF) * rdu[au] * (RSQRT_D*L2E_T));
            }
            #pragma unroll
            for (int i = 0; i < 4; ++i) {
                const int au = aur[i];
                const float C2 = acc[i][j];
                const float N = dwr[i] - C2 - g1v[au] + anqb
                              + EPSF*(swr[i] + sul[au] - 2.f*sanb) + E128F;
                const float dw2 = wqr[i] - 2.f*C2 + anqb
                                + 2.f*EPSF*(swr[i] - sanb) + E128F;
                float val = exp2f(N * rsqrtf(fmaxf(dw2, 1e-20f)) * rdu[au] * L2E_T);
                if (idr[i] == yb) val = vem[au];
                dout[obase[i] + (size_t)b*129] = val;
                zacc += (double)val;
            }
        }
        zred[tid] = zacc;
        __syncthreads();
        if (tid < 64) {
            double z = (zred[tid] + zred[tid+64]) + (zred[tid+128] + zred[tid+192]);
            #pragma unroll
            for (int m = 1; m < 64; m <<= 1) z += __shfl_xor(z, m, 64);
            if (tid == 0)
                atomicAdd(&sums[s*NSLOT + (bid & (NSLOT-1))], z);
        }
    } else {
        // ---------------- bank copy role ----------------
        float* nm1 = dout + (size_t)2*OUT_SIDE;
        float* nm2 = nm1 + (size_t)NROWS*DD;
        const int cid = bid - NGEMM;                  // 0..511
        const size_t nf4 = (size_t)NROWS*DD/4;        // 1,600,000 per bank
        const float4* s1 = (const float4*)mem1;
        const float4* s2 = (const float4*)mem2;
        float4* d1 = (float4*)nm1;
        float4* d2 = (float4*)nm2;
        #pragma unroll 2
        for (size_t i = (size_t)cid*256 + tid; i < nf4; i += (size_t)NCOPY*256) {
            d1[i] = s1[i];
            d2[i] = s2[i];
        }
    }
}

// Finish: scale out by 1/Z per side; patch the 128 momentum-updated rows.
__global__ __launch_bounds__(256) void k_finish(
    const float* __restrict__ v1, const float* __restrict__ v2,
    const float* __restrict__ mem1, const float* __restrict__ mem2,
    const int* __restrict__ y,
    float* __restrict__ dout, const double* __restrict__ sums)
{
    const int bid = blockIdx.x;
    const int tid = threadIdx.x;

    if (bid < 32) {
        const int bank = bid >> 4;
        const int wave = tid >> 6;
        const int lane = tid & 63;
        const int b    = (bid & 15) * 4 + wave;
        const float* mem = bank ? mem2 : mem1;
        const float* v   = bank ? v2 : v1;
        float* nm = dout + (size_t)2*OUT_SIDE + (size_t)bank*NROWS*DD;

        const int row = y[b];
        bool skip = false;
        for (int b2 = b + 1; b2 < NB; ++b2) skip |= (y[b2] == row);  // last occurrence wins
        if (!skip) {
            const float2 m2 = *(const float2*)(mem + (size_t)row*DD + lane*2);
            const float2 w2 = *(const float2*)(v + (size_t)b*DD + lane*2);
            float px = 0.5f*(m2.x + w2.x);
            float py = 0.5f*(m2.y + w2.y);
            float ss = px*px + py*py;
            #pragma unroll
            for (int m = 1; m < 64; m <<= 1) ss += __shfl_xor(ss, m, 64);
            const float rn = 1.0f / sqrtf(ss);
            *(float2*)(nm + (size_t)row*DD + lane*2) = make_float2(px*rn, py*rn);
        }
    } else {
        const size_t i = (size_t)(bid - 32)*256 + tid;   // float4 index into out region
        const int side = (i >= (size_t)OUT_SIDE/4) ? 1 : 0;
        double sm = 0.0;
        #pragma unroll
        for (int q = 0; q < NSLOT; ++q) sm += sums[side*NSLOT + q];
        const float f = (float)((double)OUT_SIDE / (sm * (double)NROWS));
        float4* io = (float4*)dout;
        float4 t = io[i];
        t.x *= f; t.y *= f; t.z *= f; t.w *= f;
        io[i] = t;
    }
}

extern "C" void kernel_launch(void* const* d_in, const int* in_sizes, int n_in,
                              void* d_out, int out_size, void* d_ws, size_t ws_size,
                              hipStream_t stream) {
    const float* v1   = (const float*)d_in[0];
    const float* v2   = (const float*)d_in[1];
    const float* mem1 = (const float*)d_in[2];
    const float* mem2 = (const float*)d_in[3];
    const int*   y    = (const int*)d_in[4];
    const int*   idx  = (const int*)d_in[5];
    float*  out  = (float*)d_out;
    double* sums = (double*)d_ws;

    hipMemsetAsync(d_ws, 0, 2*NSLOT*sizeof(double), stream);
    k_big<<<NGEMM + NCOPY, 256, 0, stream>>>(v1, v2, mem1, mem2, y, idx, out, sums);
    k_finish<<<32 + (2*OUT_SIDE/4)/256, 256, 0, stream>>>(v1, v2, mem1, mem2, y, out, sums);
}